// Round 1
// baseline (1866.413 us; speedup 1.0000x reference)
//
#include <hip/hip_runtime.h>

#define BATCH    32768
#define HD       256
#define TM       64
#define NTHREADS 256

// tanh(x) = 1 - 2/(exp(2x)+1); inf-safe at both tails (exp->inf => 1, exp->0 => -1)
__device__ __forceinline__ float fast_tanh(float x) {
    float t = __expf(2.0f * x);
    return 1.0f - 2.0f * __builtin_amdgcn_rcpf(t + 1.0f);
}

__global__ __launch_bounds__(NTHREADS, 2)
void cnf1d_rk4_kernel(const float* __restrict__ z0,
                      const float* __restrict__ W1,
                      const float* __restrict__ b1,
                      const float* __restrict__ W2,
                      const float* __restrict__ b2,
                      const float* __restrict__ W3,
                      const float* __restrict__ b3,
                      float* __restrict__ out)
{
    // h1 tile stored [feature][sample] so matvec reads are contiguous 32B per 8-sample group
    __shared__ float h1s[HD][TM];                 // 64 KB
    __shared__ float w10s[HD];                    // W1 row 0 (z weights)
    __shared__ float zb[TM], zc[TM], skz[TM], skd[TM], dacc[TM];
    __shared__ float kzv[TM], kdv[TM];

    const int tid = threadIdx.x;
    const int s0  = blockIdx.x * TM;

    if (tid < HD) w10s[tid] = W1[tid];
    if (tid < TM) {
        float z = z0[s0 + tid];
        zb[tid] = z; zc[tid] = z;
        skz[tid] = 0.f; skd[tid] = 0.f; dacc[tid] = 0.f;
    }
    __syncthreads();

    const float dt  = 0.25f;
    const float b3v = b3[0];

    // phase-2 mapping: thread computes 8 samples x 8 cols
    const int sb  = tid >> 5;        // 0..7  (sample block of 8)
    const int jb  = tid & 31;        // 0..31 (col block of 8)
    const int jc0 = jb * 8;
    // phase-1 mapping: thread owns one sample, 64 features
    const int p1s = tid & 63;
    const int p1q = tid >> 6;        // wave id -> uniform

    for (int step = 0; step < 4; ++step) {
        const float t0v = step * dt;
        for (int e = 0; e < 4; ++e) {
            const float te = t0v + ((e == 0) ? 0.f : (e == 3) ? dt : 0.5f * dt);

            // ---- phase 1: h1 = tanh(z*W1[0,:] + t*W1[1,:] + b1), write [feat][sample]
            {
                const float zs = zc[p1s];
                #pragma unroll
                for (int jj = 0; jj < 64; ++jj) {
                    const int j = p1q * 64 + jj;
                    const float a = fmaf(zs, w10s[j], fmaf(te, W1[HD + j], b1[j]));
                    h1s[j][p1s] = fast_tanh(a);   // consecutive lanes -> consecutive addrs
                }
            }
            __syncthreads();

            // ---- phase 2: U = H1@W2, TU = TH1@W2 (th1 recomputed on the fly)
            float u[8][8], tu[8][8];
            #pragma unroll
            for (int r = 0; r < 8; ++r)
                #pragma unroll
                for (int c = 0; c < 8; ++c) { u[r][c] = 0.f; tu[r][c] = 0.f; }

            for (int i = 0; i < HD; ++i) {
                const float4 hv0 = *(const float4*)&h1s[i][sb * 8];
                const float4 hv1 = *(const float4*)&h1s[i][sb * 8 + 4];
                const float w0i = w10s[i];
                const float h[8] = {hv0.x, hv0.y, hv0.z, hv0.w,
                                    hv1.x, hv1.y, hv1.z, hv1.w};
                float th[8];
                #pragma unroll
                for (int r = 0; r < 8; ++r) th[r] = (1.f - h[r] * h[r]) * w0i;

                const float4 wa = *(const float4*)&W2[i * HD + jc0];
                const float4 wb = *(const float4*)&W2[i * HD + jc0 + 4];
                const float w[8] = {wa.x, wa.y, wa.z, wa.w,
                                    wb.x, wb.y, wb.z, wb.w};
                #pragma unroll
                for (int r = 0; r < 8; ++r)
                    #pragma unroll
                    for (int c = 0; c < 8; ++c) {
                        u[r][c]  = fmaf(h[r],  w[c], u[r][c]);
                        tu[r][c] = fmaf(th[r], w[c], tu[r][c]);
                    }
            }

            // ---- phase 3: h2/th2 epilogue + W3 contraction (thread-local partials)
            float pdz[8], pdd[8];
            #pragma unroll
            for (int r = 0; r < 8; ++r) { pdz[r] = 0.f; pdd[r] = 0.f; }
            #pragma unroll
            for (int c = 0; c < 8; ++c) {
                const int j = jc0 + c;
                const float b2j = b2[j];
                const float w3j = W3[j];
                #pragma unroll
                for (int r = 0; r < 8; ++r) {
                    const float h2  = fast_tanh(u[r][c] + b2j);
                    const float th2 = (1.f - h2 * h2) * tu[r][c];
                    pdz[r] = fmaf(h2,  w3j, pdz[r]);
                    pdd[r] = fmaf(th2, w3j, pdd[r]);
                }
            }
            // reduce over the 32 col-blocks (lanes within each 32-lane half)
            #pragma unroll
            for (int m = 16; m >= 1; m >>= 1) {
                #pragma unroll
                for (int r = 0; r < 8; ++r) {
                    pdz[r] += __shfl_xor(pdz[r], m);
                    pdd[r] += __shfl_xor(pdd[r], m);
                }
            }
            if (jb == 0) {
                #pragma unroll
                for (int r = 0; r < 8; ++r) {
                    kzv[sb * 8 + r] = pdz[r] + b3v;
                    kdv[sb * 8 + r] = pdd[r];
                }
            }
            __syncthreads();

            // ---- phase 4: RK4 state update
            if (tid < TM) {
                const float k_z = kzv[tid], k_d = kdv[tid];
                const float cw = (e == 1 || e == 2) ? 2.f : 1.f;
                skz[tid] += cw * k_z;
                skd[tid] += cw * k_d;
                if (e < 3) {
                    const float cz = (e == 2) ? dt : 0.5f * dt;
                    zc[tid] = zb[tid] + cz * k_z;
                } else {
                    const float nz = zb[tid] + (dt / 6.f) * skz[tid];
                    zb[tid] = nz; zc[tid] = nz;
                    dacc[tid] += (dt / 6.f) * skd[tid];
                    skz[tid] = 0.f; skd[tid] = 0.f;
                }
            }
            __syncthreads();
        }
    }

    if (tid < TM) {
        out[s0 + tid]         = zb[tid];     // zf
        out[BATCH + s0 + tid] = dacc[tid];   // div_int
    }
}

extern "C" void kernel_launch(void* const* d_in, const int* in_sizes, int n_in,
                              void* d_out, int out_size, void* d_ws, size_t ws_size,
                              hipStream_t stream) {
    const float* z0 = (const float*)d_in[0];
    const float* W1 = (const float*)d_in[1];
    const float* b1 = (const float*)d_in[2];
    const float* W2 = (const float*)d_in[3];
    const float* b2 = (const float*)d_in[4];
    const float* W3 = (const float*)d_in[5];
    const float* b3 = (const float*)d_in[6];
    float* out = (float*)d_out;

    dim3 grid(BATCH / TM), block(NTHREADS);
    hipLaunchKernelGGL(cnf1d_rk4_kernel, grid, block, 0, stream,
                       z0, W1, b1, W2, b2, W3, b3, out);
}

// Round 2
// 240.807 us; speedup vs baseline: 7.7506x; 7.7506x over previous
//
#include <hip/hip_runtime.h>

#define BATCH    32768
#define HD       256
#define TM       64
#define NTHREADS 256

typedef short  short8  __attribute__((ext_vector_type(8)));
typedef float  f32x16  __attribute__((ext_vector_type(16)));

// tanh(x) = 1 - 2/(exp(2x)+1); inf-safe at both tails
__device__ __forceinline__ float fast_tanh(float x) {
    float t = __expf(2.0f * x);
    return 1.0f - 2.0f * __builtin_amdgcn_rcpf(t + 1.0f);
}

// f32 -> bf16 round-to-nearest-even (values are finite/bounded here)
__device__ __forceinline__ unsigned short f2bf(float f) {
    unsigned u = __float_as_uint(f);
    unsigned r = (u + 0x7FFFu + ((u >> 16) & 1u)) >> 16;
    return (unsigned short)r;
}

// ---- prepack W2 (f32 [256][256]) into bf16 MFMA B-fragment order in ws ----
// For v_mfma_f32_32x32x16_bf16: lane l holds B[kstep*16 + (l>>5)*8 + i][ct*32 + (l&31)]
// chunk (ct, kstep) stored at ((ct*16 + kstep)*64 + lane)*8 + i   (short8 per lane)
__global__ void prepack_w2(const float* __restrict__ W2, unsigned short* __restrict__ wsB) {
    const int k   = blockIdx.x;      // 0..255 (K row of W2)
    const int col = threadIdx.x;     // 0..255
    const unsigned short b = f2bf(W2[k * HD + col]);
    const int t  = k >> 4;           // kstep
    const int kl = k & 15;
    const int hi = kl >> 3;
    const int i  = kl & 7;
    const int n  = col >> 5;         // col-tile
    const int c  = col & 31;
    const int lane = hi * 32 + c;
    wsB[(((n * 16) + t) * 64 + lane) * 8 + i] = b;
}

__global__ __launch_bounds__(NTHREADS, 2)
void cnf1d_rk4_mfma(const float* __restrict__ z0,
                    const float* __restrict__ W1,
                    const float* __restrict__ b1,
                    const float* __restrict__ W2f,   // unused (prepacked), kept for symmetry
                    const float* __restrict__ b2,
                    const float* __restrict__ W3,
                    const float* __restrict__ b3,
                    const unsigned short* __restrict__ wsB,
                    float* __restrict__ out)
{
    // A matrix (rows 0..63 = h1 per sample, rows 64..127 = th1), bf16, XOR-swizzled:
    // short index = row*256 + (kshort ^ ((row&7)<<3))   -> byte ^ ((row&7)<<4)
    __shared__ __align__(16) short Abuf[128 * 256];       // 64 KB
    __shared__ float w1zs[HD], w1ts[HD], b1s[HD], b2s[HD], w3s[HD];
    __shared__ float zb[TM], zc[TM], skz[TM], skd[TM], dacc[TM];
    __shared__ float kzp[2][TM], kdp[2][TM];

    const int tid = threadIdx.x;
    const int s0  = blockIdx.x * TM;

    // init: stage small params + RK4 state
    w1zs[tid] = W1[tid];
    w1ts[tid] = W1[HD + tid];
    b1s[tid]  = b1[tid];
    b2s[tid]  = b2[tid];
    w3s[tid]  = W3[tid];
    if (tid < TM) {
        float z = z0[s0 + tid];
        zb[tid] = z; zc[tid] = z;
        skz[tid] = 0.f; skd[tid] = 0.f; dacc[tid] = 0.f;
    }
    __syncthreads();

    const float dt  = 0.25f;
    const float b3v = b3[0];

    // wave mapping for phase 2
    const int lane = tid & 63;
    const int ln31 = lane & 31;
    const int hi   = lane >> 5;
    const int wid  = tid >> 6;
    const int p    = wid & 1;        // sample-row-tile pair {p, p+2}
    const int ch   = wid >> 1;       // col half (128 cols)
    const int rowU = p * 32 + ln31;
    const int rowT = 64 + rowU;
    const int swz  = (rowU & 7) << 3;      // same for rowT (row+64 ≡ row mod 8)
    const int baseU = rowU * 256;
    const int baseT = rowT * 256;
    const short8* __restrict__ wsB8 = (const short8*)wsB;

    // phase-1 mapping
    const int p1s = tid & 63;              // sample
    const int p1q = tid >> 6;              // j-quarter (wave-uniform)
    const int swzW = (p1s & 7) << 3;       // write swizzle (rows s and 64+s share it)

    for (int step = 0; step < 4; ++step) {
        const float t0v = step * dt;
        for (int e = 0; e < 4; ++e) {
            const float te = t0v + ((e == 0) ? 0.f : (e == 3) ? dt : 0.5f * dt);

            // ---- phase 1: build A = [h1 ; th1] in bf16, swizzled ----
            {
                const float zs = zc[p1s];
                const int rU = p1s * 256;
                const int rT = (64 + p1s) * 256;
                #pragma unroll
                for (int g = 0; g < 8; ++g) {
                    const int j0 = p1q * 64 + g * 8;
                    short8 vU, vT;
                    #pragma unroll
                    for (int ee = 0; ee < 8; ++ee) {
                        const int j = j0 + ee;
                        const float w0 = w1zs[j];
                        const float a  = fmaf(zs, w0, fmaf(te, w1ts[j], b1s[j]));
                        const float h  = fast_tanh(a);
                        const float th = (1.f - h * h) * w0;
                        vU[ee] = (short)f2bf(h);
                        vT[ee] = (short)f2bf(th);
                    }
                    const int cs = j0 ^ swzW;
                    *(short8*)&Abuf[rU + cs] = vU;
                    *(short8*)&Abuf[rT + cs] = vT;
                }
            }
            __syncthreads();

            // ---- phase 2: [u;tu] = A @ W2 via MFMA ----
            f32x16 accU[4], accT[4];
            #pragma unroll
            for (int n = 0; n < 4; ++n)
                #pragma unroll
                for (int r = 0; r < 16; ++r) { accU[n][r] = 0.f; accT[n][r] = 0.f; }

            #pragma unroll 2
            for (int k = 0; k < 16; ++k) {
                const int ks = (k * 16 + hi * 8) ^ swz;
                const short8 aU = *(const short8*)&Abuf[baseU + ks];
                const short8 aT = *(const short8*)&Abuf[baseT + ks];
                #pragma unroll
                for (int n = 0; n < 4; ++n) {
                    const short8 bf = wsB8[((ch * 4 + n) * 16 + k) * 64 + lane];
                    accU[n] = __builtin_amdgcn_mfma_f32_32x32x16_bf16(aU, bf, accU[n], 0, 0, 0);
                    accT[n] = __builtin_amdgcn_mfma_f32_32x32x16_bf16(aT, bf, accT[n], 0, 0, 0);
                }
            }

            // ---- phase 3: epilogue tanh + W3 contraction, in-register ----
            float pdz[16], pdd[16];
            #pragma unroll
            for (int r = 0; r < 16; ++r) { pdz[r] = 0.f; pdd[r] = 0.f; }
            #pragma unroll
            for (int n = 0; n < 4; ++n) {
                const int col = ch * 128 + n * 32 + ln31;
                const float b2c = b2s[col];
                const float w3c = w3s[col];
                #pragma unroll
                for (int r = 0; r < 16; ++r) {
                    const float h2  = fast_tanh(accU[n][r] + b2c);
                    const float th2 = (1.f - h2 * h2) * accT[n][r];
                    pdz[r] = fmaf(h2,  w3c, pdz[r]);
                    pdd[r] = fmaf(th2, w3c, pdd[r]);
                }
            }
            // reduce over the 32 col-lanes (stays within each 32-lane half)
            #pragma unroll
            for (int m = 16; m >= 1; m >>= 1) {
                #pragma unroll
                for (int r = 0; r < 16; ++r) {
                    pdz[r] += __shfl_xor(pdz[r], m);
                    pdd[r] += __shfl_xor(pdd[r], m);
                }
            }
            if (ln31 == 0) {
                #pragma unroll
                for (int r = 0; r < 16; ++r) {
                    const int rin = (r & 3) + 8 * (r >> 2) + 4 * hi;  // D-row in tile
                    const int s   = p * 32 + rin;
                    kzp[ch][s] = pdz[r];
                    kdp[ch][s] = pdd[r];
                }
            }
            __syncthreads();

            // ---- phase 4: RK4 state update ----
            if (tid < TM) {
                const float k_z = kzp[0][tid] + kzp[1][tid] + b3v;
                const float k_d = kdp[0][tid] + kdp[1][tid];
                const float cw = (e == 1 || e == 2) ? 2.f : 1.f;
                skz[tid] += cw * k_z;
                skd[tid] += cw * k_d;
                if (e < 3) {
                    const float cz = (e == 2) ? dt : 0.5f * dt;
                    zc[tid] = zb[tid] + cz * k_z;
                } else {
                    const float nz = zb[tid] + (dt / 6.f) * skz[tid];
                    zb[tid] = nz; zc[tid] = nz;
                    dacc[tid] += (dt / 6.f) * skd[tid];
                    skz[tid] = 0.f; skd[tid] = 0.f;
                }
            }
            __syncthreads();
        }
    }

    if (tid < TM) {
        out[s0 + tid]         = zb[tid];     // zf
        out[BATCH + s0 + tid] = dacc[tid];   // div_int
    }
}

extern "C" void kernel_launch(void* const* d_in, const int* in_sizes, int n_in,
                              void* d_out, int out_size, void* d_ws, size_t ws_size,
                              hipStream_t stream) {
    const float* z0 = (const float*)d_in[0];
    const float* W1 = (const float*)d_in[1];
    const float* b1 = (const float*)d_in[2];
    const float* W2 = (const float*)d_in[3];
    const float* b2 = (const float*)d_in[4];
    const float* W3 = (const float*)d_in[5];
    const float* b3 = (const float*)d_in[6];
    float* out = (float*)d_out;
    unsigned short* wsB = (unsigned short*)d_ws;   // 128 KB bf16 fragment-ordered W2

    hipLaunchKernelGGL(prepack_w2, dim3(HD), dim3(HD), 0, stream, W2, wsB);
    hipLaunchKernelGGL(cnf1d_rk4_mfma, dim3(BATCH / TM), dim3(NTHREADS), 0, stream,
                       z0, W1, b1, W2, b2, W3, b3, wsB, out);
}

// Round 3
// 217.357 us; speedup vs baseline: 8.5868x; 1.1079x over previous
//
#include <hip/hip_runtime.h>
#include <hip/hip_bf16.h>

#define BATCH    32768
#define HD       256
#define TM       32
#define NTHREADS 256

typedef short  short8  __attribute__((ext_vector_type(8)));
typedef float  f32x16  __attribute__((ext_vector_type(16)));

// tanh(x) = 1 - 2/(exp(2x)+1); inf-safe at both tails
__device__ __forceinline__ float fast_tanh(float x) {
    float t = __expf(2.0f * x);
    return 1.0f - 2.0f * __builtin_amdgcn_rcpf(t + 1.0f);
}

// scalar f32 -> bf16 RNE (prepack only)
__device__ __forceinline__ unsigned short f2bf(float f) {
    unsigned u = __float_as_uint(f);
    return (unsigned short)((u + 0x7FFFu + ((u >> 16) & 1u)) >> 16);
}

// packed f32 pair -> bf16x2 (v_cvt_pk_bf16_f32 via compiler)
__device__ __forceinline__ unsigned pk2(float a, float b) {
    __hip_bfloat162 h = __float22bfloat162_rn(make_float2(a, b));
    return *reinterpret_cast<unsigned*>(&h);
}

// ---- prepack W2 (f32 [256][256]) into bf16 MFMA B-fragment order in ws ----
// For v_mfma_f32_32x32x16_bf16: lane l holds B[kstep*16 + (l>>5)*8 + i][n*32 + (l&31)]
// chunk (n, kstep) stored at ((n*16 + kstep)*64 + lane)*8 + i
__global__ void prepack_w2(const float* __restrict__ W2, unsigned short* __restrict__ wsB) {
    const int k   = blockIdx.x;      // K row of W2
    const int col = threadIdx.x;
    const unsigned short b = f2bf(W2[k * HD + col]);
    const int t  = k >> 4, kl = k & 15, hi = kl >> 3, i = kl & 7;
    const int n  = col >> 5, c = col & 31;
    wsB[(((n * 16) + t) * 64 + (hi * 32 + c)) * 8 + i] = b;
}

__global__ __launch_bounds__(NTHREADS, 4)
void cnf1d_rk4_mfma2(const float* __restrict__ z0,
                     const float* __restrict__ W1,
                     const float* __restrict__ b1,
                     const float* __restrict__ b2,
                     const float* __restrict__ W3,
                     const float* __restrict__ b3,
                     const unsigned short* __restrict__ wsB,
                     float* __restrict__ out)
{
    // A = [h1 rows 0..31 ; th1 rows 32..63], bf16, blocked-transpose layout:
    // 16B slot (granule g = j/8, row) at uint4 index g*64 + row  -> conflict-free
    __shared__ __align__(16) short Abuf[64 * 256];                // 32 KB
    __shared__ float w1zs[HD], w1ts[HD], b1s[HD], b2s[HD], w3s[HD];
    __shared__ float kzp[4][TM], kdp[4][TM];

    const int tid  = threadIdx.x;
    const int s0   = blockIdx.x * TM;
    const int lane = tid & 63;
    const int ln31 = lane & 31;
    const int hi   = lane >> 5;
    const int ch   = tid >> 6;        // wave id = 64-col quarter
    const int s    = tid & 31;        // sample owned in phase 1/4
    const int q    = (tid >> 5) & 7;  // feature block (32 features)

    w1zs[tid] = W1[tid];
    w1ts[tid] = W1[HD + tid];
    b1s[tid]  = b1[tid];
    b2s[tid]  = b2[tid];
    w3s[tid]  = W3[tid];

    // RK4 state in registers (redundant across the 8 threads sharing a sample)
    float zbr = z0[s0 + s];
    float zcr = zbr, skzr = 0.f, skdr = 0.f, daccr = 0.f;
    __syncthreads();

    const float dt  = 0.25f;
    const float b3v = b3[0];
    const short8* __restrict__ wsB8 = (const short8*)wsB;
    uint4* __restrict__ Ab4 = (uint4*)Abuf;
    const short8* __restrict__ Ab8 = (const short8*)Abuf;

    for (int it = 0; it < 16; ++it) {
        const int e    = it & 3;
        const int step = it >> 2;
        const float te = step * dt + ((e == 0) ? 0.f : ((e == 3) ? dt : 0.5f * dt));

        // ---- phase 1: h1/th1 -> bf16 A in LDS (contiguous 16B writes) ----
        #pragma unroll
        for (int g = 0; g < 4; ++g) {
            const int j0 = q * 32 + g * 8;
            float h[8], th[8];
            #pragma unroll
            for (int ee = 0; ee < 8; ++ee) {
                const int j  = j0 + ee;
                const float w0 = w1zs[j];
                const float a  = fmaf(zcr, w0, fmaf(te, w1ts[j], b1s[j]));
                const float hh = fast_tanh(a);
                h[ee]  = hh;
                th[ee] = (1.f - hh * hh) * w0;
            }
            uint4 vU, vT;
            vU.x = pk2(h[0], h[1]);  vU.y = pk2(h[2], h[3]);
            vU.z = pk2(h[4], h[5]);  vU.w = pk2(h[6], h[7]);
            vT.x = pk2(th[0], th[1]); vT.y = pk2(th[2], th[3]);
            vT.z = pk2(th[4], th[5]); vT.w = pk2(th[6], th[7]);
            const int gr = j0 >> 3;
            Ab4[gr * 64 + s]      = vU;   // U row s
            Ab4[gr * 64 + 32 + s] = vT;   // T row 32+s
        }
        __syncthreads();

        // ---- phase 2: [u;tu] = A @ W2 via MFMA (wave = 64-col quarter) ----
        f32x16 accU[2], accT[2];
        #pragma unroll
        for (int nn = 0; nn < 2; ++nn)
            #pragma unroll
            for (int r = 0; r < 16; ++r) { accU[nn][r] = 0.f; accT[nn][r] = 0.f; }

        #pragma unroll 4
        for (int k = 0; k < 16; ++k) {
            const short8 aU = Ab8[(k * 2 + hi) * 64 + ln31];
            const short8 aT = Ab8[(k * 2 + hi) * 64 + 32 + ln31];
            #pragma unroll
            for (int nn = 0; nn < 2; ++nn) {
                const short8 bf = wsB8[((ch * 2 + nn) * 16 + k) * 64 + lane];
                accU[nn] = __builtin_amdgcn_mfma_f32_32x32x16_bf16(aU, bf, accU[nn], 0, 0, 0);
                accT[nn] = __builtin_amdgcn_mfma_f32_32x32x16_bf16(aT, bf, accT[nn], 0, 0, 0);
            }
        }

        // ---- phase 3: epilogue tanh + W3 contraction ----
        float pdz[16], pdd[16];
        #pragma unroll
        for (int r = 0; r < 16; ++r) { pdz[r] = 0.f; pdd[r] = 0.f; }
        #pragma unroll
        for (int nn = 0; nn < 2; ++nn) {
            const int col   = ch * 64 + nn * 32 + ln31;
            const float b2c = b2s[col];
            const float w3c = w3s[col];
            #pragma unroll
            for (int r = 0; r < 16; ++r) {
                const float h2  = fast_tanh(accU[nn][r] + b2c);
                const float th2 = (1.f - h2 * h2) * accT[nn][r];
                pdz[r] = fmaf(h2,  w3c, pdz[r]);
                pdd[r] = fmaf(th2, w3c, pdd[r]);
            }
        }

        // halving butterfly: 32 values reduced over 32 lanes -> 1 value/lane.
        // final: lane b4..b0 holds j=(b0<<4)|(b1<<3)|(b2<<2)|(b3<<1)|b4, j=2r+zd
        float v[32];
        #pragma unroll
        for (int r = 0; r < 16; ++r) { v[2 * r] = pdz[r]; v[2 * r + 1] = pdd[r]; }
        #pragma unroll
        for (int st = 0; st < 5; ++st) {
            const int m  = 1 << st;
            const int nV = 16 >> st;               // outputs this step
            const bool up = (ln31 & m) != 0;
            #pragma unroll
            for (int i = 0; i < nV; ++i) {
                const float keep = up ? v[nV + i] : v[i];
                const float send = up ? v[i] : v[nV + i];
                v[i] = keep + __shfl_xor(send, m);
            }
        }
        {
            const int rf = ((ln31 & 1) << 3) | (((ln31 >> 1) & 1) << 2) |
                           (((ln31 >> 2) & 1) << 1) | ((ln31 >> 3) & 1);
            const int zd   = (ln31 >> 4) & 1;
            const int srow = (rf & 3) + 8 * (rf >> 2) + 4 * hi;
            if (zd) kdp[ch][srow] = v[0];
            else    kzp[ch][srow] = v[0];
        }
        __syncthreads();

        // ---- phase 4: RK4 update, in registers, all threads for own sample ----
        {
            const float k_z = kzp[0][s] + kzp[1][s] + kzp[2][s] + kzp[3][s] + b3v;
            const float k_d = kdp[0][s] + kdp[1][s] + kdp[2][s] + kdp[3][s];
            const float cw  = (e == 1 || e == 2) ? 2.f : 1.f;
            skzr += cw * k_z;
            skdr += cw * k_d;
            if (e < 3) {
                zcr = fmaf((e == 2) ? dt : 0.5f * dt, k_z, zbr);
            } else {
                zbr   = fmaf(dt / 6.f, skzr, zbr);
                zcr   = zbr;
                daccr = fmaf(dt / 6.f, skdr, daccr);
                skzr = 0.f; skdr = 0.f;
            }
        }
    }

    if (tid < TM) {
        out[s0 + tid]         = zbr;     // zf
        out[BATCH + s0 + tid] = daccr;   // div_int
    }
}

extern "C" void kernel_launch(void* const* d_in, const int* in_sizes, int n_in,
                              void* d_out, int out_size, void* d_ws, size_t ws_size,
                              hipStream_t stream) {
    const float* z0 = (const float*)d_in[0];
    const float* W1 = (const float*)d_in[1];
    const float* b1 = (const float*)d_in[2];
    const float* W2 = (const float*)d_in[3];
    const float* b2 = (const float*)d_in[4];
    const float* W3 = (const float*)d_in[5];
    const float* b3 = (const float*)d_in[6];
    float* out = (float*)d_out;
    unsigned short* wsB = (unsigned short*)d_ws;   // 128 KB bf16 fragment-ordered W2

    hipLaunchKernelGGL(prepack_w2, dim3(HD), dim3(HD), 0, stream, W2, wsB);
    hipLaunchKernelGGL(cnf1d_rk4_mfma2, dim3(BATCH / TM), dim3(NTHREADS), 0, stream,
                       z0, W1, b1, b2, W3, b3, wsB, out);
}

// Round 4
// 183.253 us; speedup vs baseline: 10.1849x; 1.1861x over previous
//
#include <hip/hip_runtime.h>
#include <hip/hip_bf16.h>

#define BATCH    32768
#define HD       256
#define TM       32
#define NTHREADS 256

#define SCL    2.8853900817779268f   // 2*log2(e): tanh(x) = 1 - 2/(exp2(SCL*x)+1)
#define SCLINV 0.3465735902799726f   // 1/SCL

typedef short  short8  __attribute__((ext_vector_type(8)));
typedef float  f32x16  __attribute__((ext_vector_type(16)));

// scalar f32 -> bf16 RNE (prepack only)
__device__ __forceinline__ unsigned short f2bf(float f) {
    unsigned u = __float_as_uint(f);
    return (unsigned short)((u + 0x7FFFu + ((u >> 16) & 1u)) >> 16);
}

// packed f32 pair -> bf16x2 (v_cvt_pk_bf16_f32)
__device__ __forceinline__ unsigned pk2(float a, float b) {
    __hip_bfloat162 h = __float22bfloat162_rn(make_float2(a, b));
    return *reinterpret_cast<unsigned*>(&h);
}

// ---- prepack W2^T (scaled by SCL) into bf16 MFMA A-fragment order ----
// A-frag for v_mfma_f32_32x32x16_bf16: lane l holds A[mt*32 + (l&31)][kstep*16 + (l>>5)*8 + i]
// where A = SCL * W2^T  (A[j][k] = SCL*W2[k][j]).
// chunk (mt, kstep) stored at ((mt*16 + kstep)*64 + lane)*8 + i
__global__ void prepack_w2t(const float* __restrict__ W2, unsigned short* __restrict__ wsA) {
    const int k = blockIdx.x;        // K row of W2
    const int j = threadIdx.x;       // output column j (row of W2^T)
    const unsigned short b = f2bf(SCL * W2[k * HD + j]);
    const int kstep = k >> 4, kl = k & 15, hi2 = kl >> 3, i = kl & 7;
    const int mt = j >> 5, jl = j & 31;
    wsA[(((mt * 16) + kstep) * 64 + (hi2 * 32 + jl)) * 8 + i] = b;
}

__global__ __launch_bounds__(NTHREADS, 4)
void cnf1d_rk4_mfma3(const float* __restrict__ z0,
                     const float* __restrict__ W1,
                     const float* __restrict__ b1,
                     const float* __restrict__ b2,
                     const float* __restrict__ W3,
                     const float* __restrict__ b3,
                     const unsigned short* __restrict__ wsA,
                     float* __restrict__ out)
{
    // B-matrix staging: [h1^T ; th1^T] bf16, blocked layout:
    // 16B slot (kgroup g = k/8, row) ; rows 0..31 = samples (U), 32..63 = tangent (T)
    __shared__ __align__(16) short Abuf[64 * 256];    // 32 KB
    __shared__ float4 pt[HD];                         // (SCL*w1z, SCL*w1t, SCL*b1, w1z) 4 KB
    __shared__ float  b2sc[HD], w3t[HD];              // SCL*b2, W3          2 KB
    __shared__ float2 kz[4][TM];                      // per-wave (pdz,pdd)  1 KB
                                                      // total 39,936 B -> 4 blocks/CU
    const int tid  = threadIdx.x;
    const int s0   = blockIdx.x * TM;
    const int lane = tid & 63;
    const int ln31 = lane & 31;
    const int hi   = lane >> 5;
    const int ch   = tid >> 6;        // wave id: owns j in [ch*64, ch*64+64)
    const int s    = tid & 31;        // owned sample
    const int q    = (tid >> 5) & 7;  // phase-1 feature block

    {
        const float w0 = W1[tid];
        pt[tid]   = make_float4(SCL * w0, SCL * W1[HD + tid], SCL * b1[tid], w0);
        b2sc[tid] = SCL * b2[tid];
        w3t[tid]  = W3[tid];
    }
    float zbr = z0[s0 + s];
    float zcr = zbr, skzr = 0.f, skdr = 0.f, daccr = 0.f;
    __syncthreads();

    const float dt  = 0.25f;
    const float b3v = b3[0];
    const short8* __restrict__ wsA8 = (const short8*)wsA;
    uint4* __restrict__ Ab4 = (uint4*)Abuf;
    const short8* __restrict__ Ab8 = (const short8*)Abuf;

    for (int it = 0; it < 16; ++it) {
        const int e    = it & 3;
        const int step = it >> 2;
        const float te = step * dt + ((e == 0) ? 0.f : ((e == 3) ? dt : 0.5f * dt));

        // ---- phase 1: h1/th1 -> bf16 staging (contiguous 16B writes) ----
        #pragma unroll
        for (int g = 0; g < 4; ++g) {
            const int j0 = q * 32 + g * 8;
            float h[8], th[8];
            #pragma unroll
            for (int ee = 0; ee < 8; ++ee) {
                const float4 p = pt[j0 + ee];
                const float a  = fmaf(zcr, p.x, fmaf(te, p.y, p.z));   // scaled pre-act
                const float ev = __builtin_amdgcn_exp2f(a);
                const float r1 = __builtin_amdgcn_rcpf(ev + 1.0f);
                const float hh = fmaf(-2.f, r1, 1.f);                  // tanh
                h[ee]  = hh;
                th[ee] = (1.f - hh * hh) * p.w;                        // dtanh * w1z
            }
            uint4 vU, vT;
            vU.x = pk2(h[0], h[1]);   vU.y = pk2(h[2], h[3]);
            vU.z = pk2(h[4], h[5]);   vU.w = pk2(h[6], h[7]);
            vT.x = pk2(th[0], th[1]); vT.y = pk2(th[2], th[3]);
            vT.z = pk2(th[4], th[5]); vT.w = pk2(th[6], th[7]);
            const int gr = j0 >> 3;
            Ab4[gr * 64 + s]      = vU;   // U row s
            Ab4[gr * 64 + 32 + s] = vT;   // T row 32+s
        }
        __syncthreads();

        // ---- phase 2: C' = (SCL*W2^T) @ [h1;th1]^T, acc pre-loaded with SCL*b2 ----
        f32x16 accU[2], accT[2];
        #pragma unroll
        for (int mt = 0; mt < 2; ++mt) {
            const int jb = ch * 64 + mt * 32 + hi * 4;
            #pragma unroll
            for (int rq = 0; rq < 4; ++rq) {
                const float4 bq = *(const float4*)&b2sc[jb + rq * 8];
                accU[mt][rq * 4 + 0] = bq.x;  accU[mt][rq * 4 + 1] = bq.y;
                accU[mt][rq * 4 + 2] = bq.z;  accU[mt][rq * 4 + 3] = bq.w;
                accT[mt][rq * 4 + 0] = 0.f;   accT[mt][rq * 4 + 1] = 0.f;
                accT[mt][rq * 4 + 2] = 0.f;   accT[mt][rq * 4 + 3] = 0.f;
            }
        }

        #pragma unroll 4
        for (int k = 0; k < 16; ++k) {
            const short8 hU = Ab8[(k * 2 + hi) * 64 + ln31];        // B-frag, U cols
            const short8 hT = Ab8[(k * 2 + hi) * 64 + 32 + ln31];   // B-frag, T cols
            #pragma unroll
            for (int mt = 0; mt < 2; ++mt) {
                const short8 aW = wsA8[((ch * 2 + mt) * 16 + k) * 64 + lane];
                accU[mt] = __builtin_amdgcn_mfma_f32_32x32x16_bf16(aW, hU, accU[mt], 0, 0, 0);
                accT[mt] = __builtin_amdgcn_mfma_f32_32x32x16_bf16(aW, hT, accT[mt], 0, 0, 0);
            }
        }

        // ---- phase 3: epilogue; j-reduction is in-lane (lane = sample) ----
        float pdz = 0.f, pdd = 0.f;
        #pragma unroll
        for (int mt = 0; mt < 2; ++mt) {
            const int jb = ch * 64 + mt * 32 + hi * 4;
            #pragma unroll
            for (int rq = 0; rq < 4; ++rq) {
                const float4 w3q = *(const float4*)&w3t[jb + rq * 8];
                #pragma unroll
                for (int rr = 0; rr < 4; ++rr) {
                    const int r = rq * 4 + rr;
                    const float ev  = __builtin_amdgcn_exp2f(accU[mt][r]);  // acc = SCL*(u+b2)
                    const float r1  = __builtin_amdgcn_rcpf(ev + 1.0f);
                    const float h2  = fmaf(-2.f, r1, 1.f);
                    const float tus = accT[mt][r];                          // SCL*tu
                    const float th2 = fmaf(-h2 * h2, tus, tus);             // (1-h2^2)*SCL*tu
                    const float w3c = ((const float*)&w3q)[rr];
                    pdz = fmaf(h2,  w3c, pdz);
                    pdd = fmaf(th2, w3c, pdd);
                }
            }
        }
        pdd *= SCLINV;                       // undo tangent scale once
        pdz += __shfl_xor(pdz, 32);          // combine hi halves (j += 4 rows)
        pdd += __shfl_xor(pdd, 32);
        if (hi == 0) kz[ch][ln31] = make_float2(pdz, pdd);
        __syncthreads();

        // ---- phase 4: RK4 update (per-thread registers, redundant per sample) ----
        {
            const float2 a0 = kz[0][s], a1 = kz[1][s], a2 = kz[2][s], a3 = kz[3][s];
            const float k_z = a0.x + a1.x + a2.x + a3.x + b3v;
            const float k_d = a0.y + a1.y + a2.y + a3.y;
            const float cw  = (e == 1 || e == 2) ? 2.f : 1.f;
            skzr += cw * k_z;
            skdr += cw * k_d;
            if (e < 3) {
                zcr = fmaf((e == 2) ? dt : 0.5f * dt, k_z, zbr);
            } else {
                zbr   = fmaf(dt / 6.f, skzr, zbr);
                zcr   = zbr;
                daccr = fmaf(dt / 6.f, skdr, daccr);
                skzr = 0.f; skdr = 0.f;
            }
        }
    }

    if (tid < TM) {
        out[s0 + tid]         = zbr;     // zf
        out[BATCH + s0 + tid] = daccr;   // div_int
    }
}

extern "C" void kernel_launch(void* const* d_in, const int* in_sizes, int n_in,
                              void* d_out, int out_size, void* d_ws, size_t ws_size,
                              hipStream_t stream) {
    const float* z0 = (const float*)d_in[0];
    const float* W1 = (const float*)d_in[1];
    const float* b1 = (const float*)d_in[2];
    const float* W2 = (const float*)d_in[3];
    const float* b2 = (const float*)d_in[4];
    const float* W3 = (const float*)d_in[5];
    const float* b3 = (const float*)d_in[6];
    float* out = (float*)d_out;
    unsigned short* wsA = (unsigned short*)d_ws;   // 128 KB bf16 A-frag W2^T (scaled)

    hipLaunchKernelGGL(prepack_w2t, dim3(HD), dim3(HD), 0, stream, W2, wsA);
    hipLaunchKernelGGL(cnf1d_rk4_mfma3, dim3(BATCH / TM), dim3(NTHREADS), 0, stream,
                       z0, W1, b1, b2, W3, b3, wsA, out);
}